// Round 15
// baseline (239.307 us; speedup 1.0000x reference)
//
#include <hip/hip_runtime.h>
#include <stdint.h>

// DynamicAgentAttention — MI355X gfx950
// B=16, C=512, N=1024 (32x32), HEADS=8, hd=64, AGENT=49 (7x7 pool)

typedef float f32x4 __attribute__((ext_vector_type(4)));
typedef short s16x8 __attribute__((ext_vector_type(8)));

typedef __attribute__((address_space(1))) void glob_v;
typedef __attribute__((address_space(3))) void lds_v;
#define GLD16(g, l) \
  __builtin_amdgcn_global_load_lds((glob_v*)(g), (lds_v*)(l), 16, 0, 0)
#define VMCNT(N) asm volatile("s_waitcnt vmcnt(" #N ")" ::: "memory")
#define BAR() __builtin_amdgcn_s_barrier()

__device__ __forceinline__ float bf2f(unsigned short u) {
  union { unsigned int i; float f; } v; v.i = ((unsigned int)u) << 16; return v.f;
}
__device__ __forceinline__ unsigned short f2bf(float f) {
  union { float f; unsigned int i; } v; v.f = f;
  return (unsigned short)((v.i + 0x7FFFu + ((v.i >> 16) & 1u)) >> 16);
}

__constant__ int ws7[7] = {0, 4, 9, 13, 18, 22, 27};
__constant__ int we7[7] = {5, 10, 14, 19, 23, 28, 32};

// ------- merged: [bid<2048] x->xT transpose + pool row-partials; [else] weights -------
__global__ __launch_bounds__(256) void k_prep(
    const float* __restrict__ x, unsigned short* __restrict__ xT,
    float* __restrict__ p_rows, const float* __restrict__ qw,
    const float* __restrict__ kvw, const float* __restrict__ pjw,
    const float* __restrict__ w1, const float* __restrict__ w2,
    unsigned short* __restrict__ Wqkv, unsigned short* __restrict__ Wpj,
    unsigned short* __restrict__ W1, unsigned short* __restrict__ W2) {
  const int bid = blockIdx.x, t = threadIdx.x;
  if (bid >= 2048) {  // weight fp32->bf16 (Wqkv = [q_w; kv_w]), 1536 blocks
    const int u = (bid - 2048) * 256 + t;
    const float* s; unsigned short* d; int su, du;
    if (u < 196608) { d = Wqkv; du = u;
      if (u < 65536) { s = qw; su = u; } else { s = kvw; su = u - 65536; } }
    else if (u < 262144) { s = pjw; su = u - 196608; d = Wpj; du = su; }
    else if (u < 327680) { s = w1; su = u - 262144; d = W1; du = su; }
    else { s = w2; su = u - 327680; d = W2; du = su; }
    const f32x4 val = ((const f32x4*)s)[su];
    uint2 pk;
    pk.x = (unsigned)f2bf(val[0]) | ((unsigned)f2bf(val[1]) << 16);
    pk.y = (unsigned)f2bf(val[2]) | ((unsigned)f2bf(val[3]) << 16);
    ((uint2*)d)[du] = pk;
    return;
  }
  __shared__ float tile[64][65];
  const int bx = bid & 15, by = (bid >> 4) & 7, bz = bid >> 7;
  const int b = bz, c0 = by * 64, n0 = bx * 64;
  const int tn = t & 63, tg = t >> 6;
#pragma unroll
  for (int i = 0; i < 16; ++i) {
    const int c_l = tg * 16 + i;
    tile[c_l][tn] = x[(b * 512 + c0 + c_l) * 1024 + n0 + tn];
  }
  __syncthreads();
#pragma unroll
  for (int i = 0; i < 16; ++i) {
    const int n_l = tg * 16 + i;
    xT[(b * 1024 + n0 + n_l) * 512 + c0 + tn] = f2bf(tile[tn][n_l]);
  }
  if (t < 128) {  // pool partials: image rows 2*bx, 2*bx+1
    const int c_l = t >> 1, rw = t & 1;
    const int rowg = bx * 2 + rw;
    const float* src = &tile[c_l][rw * 32];
    float* dst = p_rows + ((b * 512 + c0 + c_l) * 32 + rowg) * 8;
#pragma unroll
    for (int jb = 0; jb < 7; ++jb) {
      float s = 0.f;
      for (int cc = ws7[jb]; cc < we7[jb]; ++cc) s += src[cc];
      dst[jb] = s;
    }
  }
}

// ------- pooled value on the fly (identical math to old k_poolred) -------
__device__ __forceinline__ float pool_val(const float* __restrict__ p_rows,
                                          int bc, int ij) {
  const int i = ij / 7, j = ij % 7;
  float s = 0.f;
  for (int r = ws7[i]; r < we7[i]; ++r) s += p_rows[bc * 256 + r * 8 + j];
  const float area = (float)((we7[i] - ws7[i]) * (we7[j] - ws7[j]));
  return s / area;
}

// --- depthwise 3x3 (permuted gather, pool fused) + BN + ReLU -> r[b][c][49] ---
__global__ __launch_bounds__(256) void k_dw(
    const float* __restrict__ p_rows, const float* __restrict__ dww,
    const float* __restrict__ dwb, const float* __restrict__ g,
    const float* __restrict__ be, const float* __restrict__ mean,
    const float* __restrict__ var, float* __restrict__ r) {
  const int t = threadIdx.x, s = t & 63;
  if (s >= 49) return;
  const int bc = blockIdx.x * 4 + (t >> 6);
  const int b = bc >> 9, c = bc & 511;
  const int i = s / 7, j = s % 7;
  float sum = 0.f;
#pragma unroll
  for (int ki = 0; ki < 3; ++ki)
#pragma unroll
    for (int kj = 0; kj < 3; ++kj) {
      const int ii = i + ki - 1, jj = j + kj - 1;
      if (ii < 0 || ii > 6 || jj < 0 || jj > 6) continue;
      const int f = c * 49 + ii * 7 + jj;  // permuted gather (torch reshape bug kept)
      sum += dww[c * 9 + ki * 3 + kj] *
             pool_val(p_rows, b * 512 + (f & 511), f >> 9);
    }
  sum += dwb[c];
  sum = (sum - mean[c]) * rsqrtf(var[c] + 1e-5f) * g[c] + be[c];
  r[bc * 49 + s] = fmaxf(sum, 0.f);
}

// ------- pointwise 1x1 GEMM -> agent tensor Abf[bh][ag][64] bf16 -------
__global__ __launch_bounds__(256) void k_pw(const float* __restrict__ r,
                                            const float* __restrict__ w,
                                            const float* __restrict__ bias,
                                            unsigned short* __restrict__ Abf) {
  __shared__ float wl[128 * 36];
  __shared__ float rl[128 * 64];
  const int blk = blockIdx.x;
  const int b = blk >> 4, cg = blk & 15;
  const int t = threadIdx.x, wv = t >> 6, lane = t & 63;
  float acc[8];
#pragma unroll
  for (int j = 0; j < 8; ++j) acc[j] = 0.f;
  for (int ch = 0; ch < 4; ++ch) {
    __syncthreads();
#pragma unroll
    for (int u = t; u < 4096; u += 256) {
      const int co = u >> 7, ci = u & 127;
      wl[ci * 36 + co] = w[(cg * 32 + co) * 512 + ch * 128 + ci];
    }
    for (int u = t; u < 6272; u += 256) {
      const int ci = u / 49, s = u % 49;
      rl[ci * 64 + s] = r[b * 25088 + ch * 6272 + u];
    }
    __syncthreads();
#pragma unroll 4
    for (int ci = 0; ci < 128; ++ci) {
      const f32x4 w0 = *(const f32x4*)(wl + ci * 36 + wv * 8);
      const f32x4 w1 = *(const f32x4*)(wl + ci * 36 + wv * 8 + 4);
      const float rv = rl[ci * 64 + lane];
#pragma unroll
      for (int j = 0; j < 4; ++j) { acc[j] += w0[j] * rv; acc[4 + j] += w1[j] * rv; }
    }
  }
  if (lane < 49) {
    const int h = cg >> 1, d0 = (cg & 1) * 32 + wv * 8;
    s16x8 pk;
#pragma unroll
    for (int j = 0; j < 8; ++j)
      pk[j] = (short)f2bf(acc[j] + bias[cg * 32 + wv * 8 + j]);
    *(s16x8*)(Abf + ((b * 8 + h) * 64 + lane) * 64 + d0) = pk;
  }
}

// ------- bf16 MFMA GEMM: 128x128 tile, 3-deep LDS pipeline, counted vmcnt -------
// MODE 0: qkv | 1: proj | 2: mlp1 relu | 3: mlp2 +resid
template <int MODE>
__global__ __launch_bounds__(256) void k_gemm(
    const unsigned short* __restrict__ A, const unsigned short* __restrict__ B,
    unsigned short* __restrict__ oq, unsigned short* __restrict__ ok,
    unsigned short* __restrict__ ov, float* __restrict__ of,
    unsigned short* __restrict__ obf, const float* __restrict__ bias,
    const float* __restrict__ resid, float* __restrict__ dout) {
  __shared__ unsigned short As[3][4096];
  __shared__ unsigned short Bs[3][4096];
  const int t = threadIdx.x;
  constexpr int NB = (MODE == 0) ? 12 : 4;
  constexpr int NWG = NB * 128;
  const int swz = ((int)blockIdx.x & 7) * (NWG >> 3) + ((int)blockIdx.x >> 3);
  const int n0 = (swz % NB) * 128, m0 = (swz / NB) * 128;
  const int w = t >> 6, lane = t & 63;
  const int wr = w >> 1, wc = w & 1, lr = lane & 15, lg = lane >> 4;
  const unsigned short* gA = A + m0 * 512;
  const unsigned short* gB = B + n0 * 512;

  const int s_rp = t >> 3;
  const int s_g = (t & 7) ^ (s_rp & 7);
  const int s_r = (s_rp << 1) | (s_g >> 2);
  const int s_kq = (s_g & 3) * 8;
  auto stage = [&](int cur, int kt) {
    const int ko = kt * 32 + s_kq;
    GLD16(gA + s_r * 512 + ko, As[cur] + w * 512);
    GLD16(gA + (s_r + 64) * 512 + ko, As[cur] + 2048 + w * 512);
    GLD16(gB + s_r * 512 + ko, Bs[cur] + w * 512);
    GLD16(gB + (s_r + 64) * 512 + ko, Bs[cur] + 2048 + w * 512);
  };
  auto ldsw = [&](const unsigned short* hb, int rl, int lgq) -> s16x8 {
    const int rp = rl >> 1;
    const int gs = (((rl & 1) << 2) | lgq) ^ (rp & 7);
    return *(const s16x8*)(hb + rp * 64 + gs * 8);
  };

  f32x4 acc[4][4];
#pragma unroll
  for (int mi = 0; mi < 4; ++mi)
#pragma unroll
    for (int ni = 0; ni < 4; ++ni)
#pragma unroll
      for (int rr = 0; rr < 4; ++rr) acc[mi][ni][rr] = 0.f;

  stage(0, 0);
  stage(1, 1);
  for (int kt = 0; kt < 16; ++kt) {
    const int cur = kt % 3;
    if (kt < 14) {
      stage((kt + 2) % 3, kt + 2);
      VMCNT(8);
    } else if (kt == 14) {
      VMCNT(4);
    } else {
      VMCNT(0);
    }
    BAR();
    const unsigned short* Ah = As[cur] + wr * 2048;
    const unsigned short* Bh = Bs[cur] + wc * 2048;
    s16x8 af[4], bfr[4];
#pragma unroll
    for (int mi = 0; mi < 4; ++mi) af[mi] = ldsw(Ah, mi * 16 + lr, lg);
#pragma unroll
    for (int ni = 0; ni < 4; ++ni) bfr[ni] = ldsw(Bh, ni * 16 + lr, lg);
    __builtin_amdgcn_s_setprio(1);
#pragma unroll
    for (int mi = 0; mi < 4; ++mi)
#pragma unroll
      for (int ni = 0; ni < 4; ++ni)
        acc[mi][ni] = __builtin_amdgcn_mfma_f32_16x16x32_bf16(af[mi], bfr[ni],
                                                              acc[mi][ni], 0, 0, 0);
    __builtin_amdgcn_s_setprio(0);
    BAR();
  }

#pragma unroll
  for (int mi = 0; mi < 4; ++mi)
#pragma unroll
    for (int ni = 0; ni < 4; ++ni)
#pragma unroll
      for (int rr = 0; rr < 4; ++rr) {
        const int gm = m0 + wr * 64 + mi * 16 + lg * 4 + rr;
        const int gn = n0 + wc * 64 + ni * 16 + lr;
        const float val = acc[mi][ni][rr];
        if (MODE == 0) {
          const int b = gm >> 10, n = gm & 1023;
          const int hh = (gn >> 6) & 7, dd = gn & 63;
          const int idx = ((b * 8 + hh) * 1024 + n) * 64 + dd;
          const unsigned short bv = f2bf(val);
          if (gn < 512) oq[idx] = bv;
          else if (gn < 1024) ok[idx] = bv;
          else ov[idx] = bv;
        } else if (MODE == 1) {
          const float v2 = val + bias[gn];
          of[gm * 512 + gn] = v2;
          obf[gm * 512 + gn] = f2bf(v2);
        } else if (MODE == 2) {
          const float v2 = fmaxf(val + bias[gn], 0.f);
          obf[gm * 512 + gn] = f2bf(v2);
        } else {
          dout[gm * 512 + gn] = val + bias[gn] + resid[gm * 512 + gn];
        }
      }
}

// ------- stage-1 agent flash: numT[qtr][bh][d][ag], den[qtr][bh][ag] -------
__global__ __launch_bounds__(256) void k_aflash(
    const unsigned short* __restrict__ Abf, const unsigned short* __restrict__ kbf,
    const unsigned short* __restrict__ vbf, float* __restrict__ numT,
    float* __restrict__ denG) {
  __shared__ unsigned short A_lds[64 * 72];   // [ag][d]
  __shared__ unsigned short K_lds[64 * 72];   // [n][d] per chunk
  __shared__ unsigned short VT_lds[64 * 72];  // [d][n] per chunk (transposed stage)
  __shared__ unsigned short P_lds[64 * 72];   // [ag][n], wave strips
  const int blk = blockIdx.x;
  const int bh = blk >> 2, qtr = blk & 3;
  const int t = threadIdx.x, w = t >> 6, lane = t & 63;
  const int lr = lane & 15, lg = lane >> 4;

  for (int u = t; u < 15 * 72; u += 256) A_lds[49 * 72 + u] = 0;
  for (int u = t; u < 392; u += 256) {  // 49 rows x 8 granules, vector copy
    const int row = u >> 3, q = u & 7;
    *(s16x8*)(A_lds + row * 72 + q * 8) = *(const s16x8*)(Abf + bh * 4096 + u * 8);
  }

  const unsigned short* kbase = kbf + bh * 65536 + qtr * 256 * 64;
  const unsigned short* vbase = vbf + bh * 65536 + qtr * 256 * 64;

  f32x4 num[4];
#pragma unroll
  for (int ni = 0; ni < 4; ++ni)
#pragma unroll
    for (int rr = 0; rr < 4; ++rr) num[ni][rr] = 0.f;
  float den[4] = {0.f, 0.f, 0.f, 0.f};

  for (int c = 0; c < 4; ++c) {
    const int n0 = c * 64;
    __syncthreads();
#pragma unroll
    for (int u = t; u < 512; u += 256) {
      const int rw = u >> 3, qq = u & 7;
      *(s16x8*)(K_lds + rw * 72 + qq * 8) =
          *(const s16x8*)(kbase + (n0 + rw) * 64 + qq * 8);
    }
#pragma unroll
    for (int u = t; u < 512; u += 256) {
      const int n_l = u & 63, qq = u >> 6;
      const s16x8 v = *(const s16x8*)(vbase + (n0 + n_l) * 64 + qq * 8);
#pragma unroll
      for (int j = 0; j < 8; ++j)
        VT_lds[(qq * 8 + j) * 72 + n_l] = (unsigned short)v[j];
    }
    __syncthreads();
    f32x4 s[4];
#pragma unroll
    for (int ni = 0; ni < 4; ++ni)
#pragma unroll
      for (int rr = 0; rr < 4; ++rr) s[ni][rr] = 0.f;
#pragma unroll
    for (int kk = 0; kk < 2; ++kk) {
      const s16x8 afr = *(const s16x8*)(A_lds + (w * 16 + lr) * 72 + kk * 32 + lg * 8);
#pragma unroll
      for (int ni = 0; ni < 4; ++ni) {
        const s16x8 bfr =
            *(const s16x8*)(K_lds + (ni * 16 + lr) * 72 + kk * 32 + lg * 8);
        s[ni] = __builtin_amdgcn_mfma_f32_16x16x32_bf16(afr, bfr, s[ni], 0, 0, 0);
      }
    }
#pragma unroll
    for (int ni = 0; ni < 4; ++ni)
#pragma unroll
      for (int rr = 0; rr < 4; ++rr) {
        const float p = __expf(s[ni][rr] * 0.125f);
        den[rr] += p;
        P_lds[(w * 16 + lg * 4 + rr) * 72 + ni * 16 + lr] = f2bf(p);
      }
#pragma unroll
    for (int kk = 0; kk < 2; ++kk) {
      const s16x8 pa = *(const s16x8*)(P_lds + (w * 16 + lr) * 72 + kk * 32 + lg * 8);
#pragma unroll
      for (int ni = 0; ni < 4; ++ni) {
        const s16x8 vfr =
            *(const s16x8*)(VT_lds + (ni * 16 + lr) * 72 + kk * 32 + lg * 8);
        num[ni] = __builtin_amdgcn_mfma_f32_16x16x32_bf16(pa, vfr, num[ni], 0, 0, 0);
      }
    }
  }
#pragma unroll
  for (int rr = 0; rr < 4; ++rr) {
#pragma unroll
    for (int o = 1; o < 16; o <<= 1) den[rr] += __shfl_xor(den[rr], o, 64);
  }
  const int obase = (qtr * 128 + bh) * 4096;
#pragma unroll
  for (int ni = 0; ni < 4; ++ni)
    *(f32x4*)(numT + obase + (ni * 16 + lr) * 64 + w * 16 + lg * 4) = num[ni];
  if (lr == 0) {
    f32x4 dv;
#pragma unroll
    for (int rr = 0; rr < 4; ++rr) dv[rr] = den[rr];
    *(f32x4*)(denG + (qtr * 128 + bh) * 64 + w * 16 + lg * 4) = dv;
  }
}

// ------- stage-2 MFMA (aggfin fused): enh[n][C] = softmax49(q.A^T) @ agg -------
__global__ __launch_bounds__(256) void k_attn2(
    const unsigned short* __restrict__ Abf, const float* __restrict__ numT,
    const float* __restrict__ denG, const unsigned short* __restrict__ qbf,
    unsigned short* __restrict__ enh) {
  __shared__ unsigned short A_lds[64 * 72];       // [ag][d]
  __shared__ unsigned short G_lds[64 * 72];       // [d][ag], pre-scaled
  __shared__ unsigned short P2_lds[4][64 * 72];   // per-wave [n][ag]
  __shared__ float invden[64];
  const int blk = blockIdx.x;
  const int bh = blk >> 2, nq = blk & 3;
  const int b = bh >> 3, h = bh & 7;
  const int t = threadIdx.x, w = t >> 6, lane = t & 63;
  const int lr = lane & 15, lg = lane >> 4;

  if (t < 64)
    invden[t] = 1.f / (denG[bh * 64 + t] + denG[8192 + bh * 64 + t] +
                       denG[16384 + bh * 64 + t] + denG[24576 + bh * 64 + t]);
  for (int u = t; u < 15 * 72; u += 256) A_lds[49 * 72 + u] = 0;
  for (int u = t; u < 392; u += 256) {
    const int row = u >> 3, q = u & 7;
    *(s16x8*)(A_lds + row * 72 + q * 8) = *(const s16x8*)(Abf + bh * 4096 + u * 8);
  }
  __syncthreads();  // invden ready
  for (int u = t; u < 4096; u += 256) {  // aggfin fused (same math as old kernel)
    const int d = u >> 6, ag = u & 63;
    const float v = (numT[bh * 4096 + u] + numT[524288 + bh * 4096 + u] +
                     numT[1048576 + bh * 4096 + u] + numT[1572864 + bh * 4096 + u]) *
                    invden[ag];
    G_lds[d * 72 + ag] = f2bf(v);
  }
  __syncthreads();

  const int nbase = nq * 256 + w * 64;
  const unsigned short* qp = qbf + (bh * 1024 + nbase) * 64;
  s16x8 qf[4][2];
#pragma unroll
  for (int mi = 0; mi < 4; ++mi)
#pragma unroll
    for (int kk = 0; kk < 2; ++kk)
      qf[mi][kk] = *(const s16x8*)(qp + (mi * 16 + lr) * 64 + kk * 32 + lg * 8);

  f32x4 L[4][4];
#pragma unroll
  for (int mi = 0; mi < 4; ++mi)
#pragma unroll
    for (int ni = 0; ni < 4; ++ni)
#pragma unroll
      for (int rr = 0; rr < 4; ++rr) L[mi][ni][rr] = 0.f;
#pragma unroll
  for (int kk = 0; kk < 2; ++kk)
#pragma unroll
    for (int ni = 0; ni < 4; ++ni) {
      const s16x8 bfr = *(const s16x8*)(A_lds + (ni * 16 + lr) * 72 + kk * 32 + lg * 8);
#pragma unroll
      for (int mi = 0; mi < 4; ++mi)
        L[mi][ni] = __builtin_amdgcn_mfma_f32_16x16x32_bf16(qf[mi][kk], bfr,
                                                            L[mi][ni], 0, 0, 0);
    }
  unsigned short* pw = P2_lds[w];
#pragma unroll
  for (int mi = 0; mi < 4; ++mi) {
    float ps[4][4];
    float rs[4];
#pragma unroll
    for (int rr = 0; rr < 4; ++rr) rs[rr] = 0.f;
#pragma unroll
    for (int ni = 0; ni < 4; ++ni) {
      const bool valid = (ni < 3) | (lr == 0);
#pragma unroll
      for (int rr = 0; rr < 4; ++rr) {
        const float p = valid ? __expf(L[mi][ni][rr] * 0.125f) : 0.f;
        ps[ni][rr] = p;
        rs[rr] += p;
      }
    }
#pragma unroll
    for (int rr = 0; rr < 4; ++rr) {
#pragma unroll
      for (int o = 1; o < 16; o <<= 1) rs[rr] += __shfl_xor(rs[rr], o, 64);
      rs[rr] = 1.f / rs[rr];
    }
#pragma unroll
    for (int ni = 0; ni < 4; ++ni)
#pragma unroll
      for (int rr = 0; rr < 4; ++rr)
        pw[(mi * 16 + lg * 4 + rr) * 72 + ni * 16 + lr] = f2bf(ps[ni][rr] * rs[rr]);
  }
#pragma unroll
  for (int mi = 0; mi < 4; ++mi) {
    f32x4 e[4];
#pragma unroll
    for (int ni = 0; ni < 4; ++ni)
#pragma unroll
      for (int rr = 0; rr < 4; ++rr) e[ni][rr] = 0.f;
#pragma unroll
    for (int kk = 0; kk < 2; ++kk) {
      const s16x8 pa = *(const s16x8*)(pw + (mi * 16 + lr) * 72 + kk * 32 + lg * 8);
#pragma unroll
      for (int ni = 0; ni < 4; ++ni) {
        const s16x8 gb = *(const s16x8*)(G_lds + (ni * 16 + lr) * 72 + kk * 32 + lg * 8);
        e[ni] = __builtin_amdgcn_mfma_f32_16x16x32_bf16(pa, gb, e[ni], 0, 0, 0);
      }
    }
#pragma unroll
    for (int ni = 0; ni < 4; ++ni)
#pragma unroll
      for (int rr = 0; rr < 4; ++rr) {
        const int n = nbase + mi * 16 + lg * 4 + rr;
        enh[(b * 1024 + n) * 512 + h * 64 + ni * 16 + lr] = f2bf(e[ni][rr]);
      }
  }
}

extern "C" void kernel_launch(void* const* d_in, const int* in_sizes, int n_in,
                              void* d_out, int out_size, void* d_ws, size_t ws_size,
                              hipStream_t stream) {
  const float* x    = (const float*)d_in[0];
  const float* q_w  = (const float*)d_in[3];
  const float* kv_w = (const float*)d_in[4];
  const float* dw_w = (const float*)d_in[5];
  const float* dw_b = (const float*)d_in[6];
  const float* bn_g = (const float*)d_in[7];
  const float* bn_b = (const float*)d_in[8];
  const float* bn_m = (const float*)d_in[9];
  const float* bn_v = (const float*)d_in[10];
  const float* pw_w = (const float*)d_in[11];
  const float* pw_b = (const float*)d_in[12];
  const float* pj_w = (const float*)d_in[13];
  const float* pj_b = (const float*)d_in[14];
  const float* e1_w = (const float*)d_in[15];
  const float* e1_b = (const float*)d_in[16];
  const float* e2_w = (const float*)d_in[17];
  const float* e2_b = (const float*)d_in[18];

  char* base = (char*)d_ws;
  size_t off = 0;
  auto alloc = [&](size_t bytes) -> void* {
    void* r = base + off;
    off += (bytes + 255) & ~(size_t)255;
    return r;
  };
  unsigned short* Wqkv = (unsigned short*)alloc(786432ull * 2);
  unsigned short* Wpj  = (unsigned short*)alloc(262144ull * 2);
  unsigned short* W1   = (unsigned short*)alloc(262144ull * 2);
  unsigned short* W2   = (unsigned short*)alloc(262144ull * 2);
  unsigned short* xT   = (unsigned short*)alloc(8388608ull * 2);
  unsigned short* qb   = (unsigned short*)alloc(8388608ull * 2);
  unsigned short* kb   = (unsigned short*)alloc(8388608ull * 2);
  unsigned short* vb   = (unsigned short*)alloc(8388608ull * 2);
  float* prow = (float*)alloc(2097152ull * 4);   // 16*512*32*8
  float* rbuf = (float*)alloc(401408ull * 4);
  unsigned short* Abf = (unsigned short*)alloc(524288ull * 2);  // [bh][ag64][64]
  float* numT = (float*)alloc(2097152ull * 4);   // 4 qtr partials
  float* denG = (float*)alloc(32768ull * 4);
  unsigned short* enh  = (unsigned short*)alloc(8388608ull * 2);
  float* xout = (float*)alloc(8388608ull * 4);
  unsigned short* xoutb = (unsigned short*)alloc(8388608ull * 2);
  unsigned short* h1    = (unsigned short*)alloc(8388608ull * 2);
  (void)ws_size; (void)in_sizes; (void)n_in; (void)out_size;

  k_prep<<<3584, 256, 0, stream>>>(x, xT, prow, q_w, kv_w, pj_w, e1_w, e2_w,
                                   Wqkv, Wpj, W1, W2);
  k_dw<<<2048, 256, 0, stream>>>(prow, dw_w, dw_b, bn_g, bn_b, bn_m, bn_v, rbuf);
  k_pw<<<256, 256, 0, stream>>>(rbuf, pw_w, pw_b, Abf);
  k_gemm<0><<<1536, 256, 0, stream>>>(xT, Wqkv, qb, kb, vb,
                                      nullptr, nullptr, nullptr, nullptr, nullptr);
  k_aflash<<<512, 256, 0, stream>>>(Abf, kb, vb, numT, denG);
  k_attn2<<<512, 256, 0, stream>>>(Abf, numT, denG, qb, enh);
  k_gemm<1><<<512, 256, 0, stream>>>(enh, Wpj, nullptr, nullptr, nullptr,
                                     xout, xoutb, pj_b, nullptr, nullptr);
  k_gemm<2><<<512, 256, 0, stream>>>(xoutb, W1, nullptr, nullptr, nullptr,
                                     nullptr, h1, e1_b, nullptr, nullptr);
  k_gemm<3><<<512, 256, 0, stream>>>(h1, W2, nullptr, nullptr, nullptr,
                                     nullptr, nullptr, e2_b, xout, (float*)d_out);
}

// Round 16
// 184.716 us; speedup vs baseline: 1.2955x; 1.2955x over previous
//
#include <hip/hip_runtime.h>
#include <stdint.h>

// DynamicAgentAttention — MI355X gfx950
// B=16, C=512, N=1024 (32x32), HEADS=8, hd=64, AGENT=49 (7x7 pool)

typedef float f32x4 __attribute__((ext_vector_type(4)));
typedef short s16x8 __attribute__((ext_vector_type(8)));

typedef __attribute__((address_space(1))) void glob_v;
typedef __attribute__((address_space(3))) void lds_v;
#define GLD16(g, l) \
  __builtin_amdgcn_global_load_lds((glob_v*)(g), (lds_v*)(l), 16, 0, 0)
#define VMCNT(N) asm volatile("s_waitcnt vmcnt(" #N ")" ::: "memory")
#define BAR() __builtin_amdgcn_s_barrier()

__device__ __forceinline__ float bf2f(unsigned short u) {
  union { unsigned int i; float f; } v; v.i = ((unsigned int)u) << 16; return v.f;
}
__device__ __forceinline__ unsigned short f2bf(float f) {
  union { float f; unsigned int i; } v; v.f = f;
  return (unsigned short)((v.i + 0x7FFFu + ((v.i >> 16) & 1u)) >> 16);
}

__constant__ int ws7[7] = {0, 4, 9, 13, 18, 22, 27};
__constant__ int we7[7] = {5, 10, 14, 19, 23, 28, 32};

// ------- merged: [bid<2048] x->xT transpose + pool row-partials; [else] weights -------
__global__ __launch_bounds__(256) void k_prep(
    const float* __restrict__ x, unsigned short* __restrict__ xT,
    float* __restrict__ p_rows, const float* __restrict__ qw,
    const float* __restrict__ kvw, const float* __restrict__ pjw,
    const float* __restrict__ w1, const float* __restrict__ w2,
    unsigned short* __restrict__ Wqkv, unsigned short* __restrict__ Wpj,
    unsigned short* __restrict__ W1, unsigned short* __restrict__ W2) {
  const int bid = blockIdx.x, t = threadIdx.x;
  if (bid >= 2048) {  // weight fp32->bf16 (Wqkv = [q_w; kv_w]), 1536 blocks
    const int u = (bid - 2048) * 256 + t;
    const float* s; unsigned short* d; int su, du;
    if (u < 196608) { d = Wqkv; du = u;
      if (u < 65536) { s = qw; su = u; } else { s = kvw; su = u - 65536; } }
    else if (u < 262144) { s = pjw; su = u - 196608; d = Wpj; du = su; }
    else if (u < 327680) { s = w1; su = u - 262144; d = W1; du = su; }
    else { s = w2; su = u - 327680; d = W2; du = su; }
    const f32x4 val = ((const f32x4*)s)[su];
    uint2 pk;
    pk.x = (unsigned)f2bf(val[0]) | ((unsigned)f2bf(val[1]) << 16);
    pk.y = (unsigned)f2bf(val[2]) | ((unsigned)f2bf(val[3]) << 16);
    ((uint2*)d)[du] = pk;
    return;
  }
  __shared__ float tile[64][65];
  const int bx = bid & 15, by = (bid >> 4) & 7, bz = bid >> 7;
  const int b = bz, c0 = by * 64, n0 = bx * 64;
  const int tn = t & 63, tg = t >> 6;
#pragma unroll
  for (int i = 0; i < 16; ++i) {
    const int c_l = tg * 16 + i;
    tile[c_l][tn] = x[(b * 512 + c0 + c_l) * 1024 + n0 + tn];
  }
  __syncthreads();
#pragma unroll
  for (int i = 0; i < 16; ++i) {
    const int n_l = tg * 16 + i;
    xT[(b * 1024 + n0 + n_l) * 512 + c0 + tn] = f2bf(tile[tn][n_l]);
  }
  if (t < 128) {  // pool partials: image rows 2*bx, 2*bx+1
    const int c_l = t >> 1, rw = t & 1;
    const int rowg = bx * 2 + rw;
    const float* src = &tile[c_l][rw * 32];
    float* dst = p_rows + ((b * 512 + c0 + c_l) * 32 + rowg) * 8;
#pragma unroll
    for (int jb = 0; jb < 7; ++jb) {
      float s = 0.f;
      for (int cc = ws7[jb]; cc < we7[jb]; ++cc) s += src[cc];
      dst[jb] = s;
    }
  }
}

// ------- pool reduce: p[b][c][49] from p_rows -------
__global__ __launch_bounds__(256) void k_poolred(const float* __restrict__ p_rows,
                                                 float* __restrict__ p) {
  const int u = blockIdx.x * 256 + threadIdx.x;
  if (u >= 401408) return;
  const int bc = u / 49, ij = u % 49;
  const int i = ij / 7, j = ij % 7;
  float s = 0.f;
  for (int r = ws7[i]; r < we7[i]; ++r) s += p_rows[bc * 256 + r * 8 + j];
  const float area = (float)((we7[i] - ws7[i]) * (we7[j] - ws7[j]));
  p[u] = s / area;
}

// ------- depthwise 3x3 SAME on permuted input + BN + ReLU -> r[b][c][49] -------
__global__ __launch_bounds__(256) void k_dw(
    const float* __restrict__ p, const float* __restrict__ dww,
    const float* __restrict__ dwb, const float* __restrict__ g,
    const float* __restrict__ be, const float* __restrict__ mean,
    const float* __restrict__ var, float* __restrict__ r) {
  const int t = threadIdx.x, s = t & 63;
  if (s >= 49) return;
  const int bc = blockIdx.x * 4 + (t >> 6);
  const int b = bc >> 9, c = bc & 511;
  const int i = s / 7, j = s % 7;
  float sum = 0.f;
#pragma unroll
  for (int ki = 0; ki < 3; ++ki)
#pragma unroll
    for (int kj = 0; kj < 3; ++kj) {
      const int ii = i + ki - 1, jj = j + kj - 1;
      if (ii < 0 || ii > 6 || jj < 0 || jj > 6) continue;
      const int f = c * 49 + ii * 7 + jj;  // permuted gather (torch reshape bug kept)
      sum += dww[c * 9 + ki * 3 + kj] * p[(b * 512 + (f & 511)) * 49 + (f >> 9)];
    }
  sum += dwb[c];
  sum = (sum - mean[c]) * rsqrtf(var[c] + 1e-5f) * g[c] + be[c];
  r[bc * 49 + s] = fmaxf(sum, 0.f);
}

// ------- pointwise 1x1 GEMM -> agent tensor Abf[bh][ag][64] bf16 -------
__global__ __launch_bounds__(256) void k_pw(const float* __restrict__ r,
                                            const float* __restrict__ w,
                                            const float* __restrict__ bias,
                                            unsigned short* __restrict__ Abf) {
  __shared__ float wl[128 * 36];
  __shared__ float rl[128 * 64];
  const int blk = blockIdx.x;
  const int b = blk >> 4, cg = blk & 15;
  const int t = threadIdx.x, wv = t >> 6, lane = t & 63;
  float acc[8];
#pragma unroll
  for (int j = 0; j < 8; ++j) acc[j] = 0.f;
  for (int ch = 0; ch < 4; ++ch) {
    __syncthreads();
#pragma unroll
    for (int u = t; u < 4096; u += 256) {
      const int co = u >> 7, ci = u & 127;
      wl[ci * 36 + co] = w[(cg * 32 + co) * 512 + ch * 128 + ci];
    }
    for (int u = t; u < 6272; u += 256) {
      const int ci = u / 49, s = u % 49;
      rl[ci * 64 + s] = r[b * 25088 + ch * 6272 + u];
    }
    __syncthreads();
#pragma unroll 4
    for (int ci = 0; ci < 128; ++ci) {
      const f32x4 w0 = *(const f32x4*)(wl + ci * 36 + wv * 8);
      const f32x4 w1 = *(const f32x4*)(wl + ci * 36 + wv * 8 + 4);
      const float rv = rl[ci * 64 + lane];
#pragma unroll
      for (int j = 0; j < 4; ++j) { acc[j] += w0[j] * rv; acc[4 + j] += w1[j] * rv; }
    }
  }
  if (lane < 49) {
    const int h = cg >> 1, d0 = (cg & 1) * 32 + wv * 8;
    s16x8 pk;
#pragma unroll
    for (int j = 0; j < 8; ++j)
      pk[j] = (short)f2bf(acc[j] + bias[cg * 32 + wv * 8 + j]);
    *(s16x8*)(Abf + ((b * 8 + h) * 64 + lane) * 64 + d0) = pk;
  }
}

// ------- bf16 MFMA GEMM: 128x128 tile, 3-deep LDS pipeline, counted vmcnt -------
// MODE 0: qkv | 1: proj | 2: mlp1 relu | 3: mlp2 +resid
template <int MODE>
__global__ __launch_bounds__(256) void k_gemm(
    const unsigned short* __restrict__ A, const unsigned short* __restrict__ B,
    unsigned short* __restrict__ oq, unsigned short* __restrict__ ok,
    unsigned short* __restrict__ ov, float* __restrict__ of,
    unsigned short* __restrict__ obf, const float* __restrict__ bias,
    const float* __restrict__ resid, float* __restrict__ dout) {
  __shared__ unsigned short As[3][4096];
  __shared__ unsigned short Bs[3][4096];
  const int t = threadIdx.x;
  constexpr int NB = (MODE == 0) ? 12 : 4;
  constexpr int NWG = NB * 128;
  const int swz = ((int)blockIdx.x & 7) * (NWG >> 3) + ((int)blockIdx.x >> 3);
  const int n0 = (swz % NB) * 128, m0 = (swz / NB) * 128;
  const int w = t >> 6, lane = t & 63;
  const int wr = w >> 1, wc = w & 1, lr = lane & 15, lg = lane >> 4;
  const unsigned short* gA = A + m0 * 512;
  const unsigned short* gB = B + n0 * 512;

  const int s_rp = t >> 3;
  const int s_g = (t & 7) ^ (s_rp & 7);
  const int s_r = (s_rp << 1) | (s_g >> 2);
  const int s_kq = (s_g & 3) * 8;
  auto stage = [&](int cur, int kt) {
    const int ko = kt * 32 + s_kq;
    GLD16(gA + s_r * 512 + ko, As[cur] + w * 512);
    GLD16(gA + (s_r + 64) * 512 + ko, As[cur] + 2048 + w * 512);
    GLD16(gB + s_r * 512 + ko, Bs[cur] + w * 512);
    GLD16(gB + (s_r + 64) * 512 + ko, Bs[cur] + 2048 + w * 512);
  };
  auto ldsw = [&](const unsigned short* hb, int rl, int lgq) -> s16x8 {
    const int rp = rl >> 1;
    const int gs = (((rl & 1) << 2) | lgq) ^ (rp & 7);
    return *(const s16x8*)(hb + rp * 64 + gs * 8);
  };

  f32x4 acc[4][4];
#pragma unroll
  for (int mi = 0; mi < 4; ++mi)
#pragma unroll
    for (int ni = 0; ni < 4; ++ni)
#pragma unroll
      for (int rr = 0; rr < 4; ++rr) acc[mi][ni][rr] = 0.f;

  stage(0, 0);
  stage(1, 1);
  for (int kt = 0; kt < 16; ++kt) {
    const int cur = kt % 3;
    if (kt < 14) {
      stage((kt + 2) % 3, kt + 2);
      VMCNT(8);
    } else if (kt == 14) {
      VMCNT(4);
    } else {
      VMCNT(0);
    }
    BAR();
    const unsigned short* Ah = As[cur] + wr * 2048;
    const unsigned short* Bh = Bs[cur] + wc * 2048;
    s16x8 af[4], bfr[4];
#pragma unroll
    for (int mi = 0; mi < 4; ++mi) af[mi] = ldsw(Ah, mi * 16 + lr, lg);
#pragma unroll
    for (int ni = 0; ni < 4; ++ni) bfr[ni] = ldsw(Bh, ni * 16 + lr, lg);
    __builtin_amdgcn_s_setprio(1);
#pragma unroll
    for (int mi = 0; mi < 4; ++mi)
#pragma unroll
      for (int ni = 0; ni < 4; ++ni)
        acc[mi][ni] = __builtin_amdgcn_mfma_f32_16x16x32_bf16(af[mi], bfr[ni],
                                                              acc[mi][ni], 0, 0, 0);
    __builtin_amdgcn_s_setprio(0);
    BAR();
  }

#pragma unroll
  for (int mi = 0; mi < 4; ++mi)
#pragma unroll
    for (int ni = 0; ni < 4; ++ni)
#pragma unroll
      for (int rr = 0; rr < 4; ++rr) {
        const int gm = m0 + wr * 64 + mi * 16 + lg * 4 + rr;
        const int gn = n0 + wc * 64 + ni * 16 + lr;
        const float val = acc[mi][ni][rr];
        if (MODE == 0) {
          const int b = gm >> 10, n = gm & 1023;
          const int hh = (gn >> 6) & 7, dd = gn & 63;
          const int idx = ((b * 8 + hh) * 1024 + n) * 64 + dd;
          const unsigned short bv = f2bf(val);
          if (gn < 512) oq[idx] = bv;
          else if (gn < 1024) ok[idx] = bv;
          else ov[idx] = bv;
        } else if (MODE == 1) {
          const float v2 = val + bias[gn];
          of[gm * 512 + gn] = v2;
          obf[gm * 512 + gn] = f2bf(v2);
        } else if (MODE == 2) {
          const float v2 = fmaxf(val + bias[gn], 0.f);
          obf[gm * 512 + gn] = f2bf(v2);
        } else {
          dout[gm * 512 + gn] = val + bias[gn] + resid[gm * 512 + gn];
        }
      }
}

// ------- stage-1 agent flash: numT[qtr][bh][d][ag], den[qtr][bh][ag] -------
__global__ __launch_bounds__(256) void k_aflash(
    const unsigned short* __restrict__ Abf, const unsigned short* __restrict__ kbf,
    const unsigned short* __restrict__ vbf, float* __restrict__ numT,
    float* __restrict__ denG) {
  __shared__ unsigned short A_lds[64 * 72];   // [ag][d]
  __shared__ unsigned short K_lds[64 * 72];   // [n][d] per chunk
  __shared__ unsigned short VT_lds[64 * 72];  // [d][n] per chunk (transposed stage)
  __shared__ unsigned short P_lds[64 * 72];   // [ag][n], wave strips
  const int blk = blockIdx.x;
  const int bh = blk >> 2, qtr = blk & 3;
  const int t = threadIdx.x, w = t >> 6, lane = t & 63;
  const int lr = lane & 15, lg = lane >> 4;

  for (int u = t; u < 15 * 72; u += 256) A_lds[49 * 72 + u] = 0;
  for (int u = t; u < 392; u += 256) {  // 49 rows x 8 granules, vector copy
    const int row = u >> 3, q = u & 7;
    *(s16x8*)(A_lds + row * 72 + q * 8) = *(const s16x8*)(Abf + bh * 4096 + u * 8);
  }

  const unsigned short* kbase = kbf + bh * 65536 + qtr * 256 * 64;
  const unsigned short* vbase = vbf + bh * 65536 + qtr * 256 * 64;

  f32x4 num[4];
#pragma unroll
  for (int ni = 0; ni < 4; ++ni)
#pragma unroll
    for (int rr = 0; rr < 4; ++rr) num[ni][rr] = 0.f;
  float den[4] = {0.f, 0.f, 0.f, 0.f};

  for (int c = 0; c < 4; ++c) {
    const int n0 = c * 64;
    __syncthreads();
#pragma unroll
    for (int u = t; u < 512; u += 256) {
      const int rw = u >> 3, qq = u & 7;
      *(s16x8*)(K_lds + rw * 72 + qq * 8) =
          *(const s16x8*)(kbase + (n0 + rw) * 64 + qq * 8);
    }
#pragma unroll
    for (int u = t; u < 512; u += 256) {
      const int n_l = u & 63, qq = u >> 6;
      const s16x8 v = *(const s16x8*)(vbase + (n0 + n_l) * 64 + qq * 8);
#pragma unroll
      for (int j = 0; j < 8; ++j)
        VT_lds[(qq * 8 + j) * 72 + n_l] = (unsigned short)v[j];
    }
    __syncthreads();
    f32x4 s[4];
#pragma unroll
    for (int ni = 0; ni < 4; ++ni)
#pragma unroll
      for (int rr = 0; rr < 4; ++rr) s[ni][rr] = 0.f;
#pragma unroll
    for (int kk = 0; kk < 2; ++kk) {
      const s16x8 afr = *(const s16x8*)(A_lds + (w * 16 + lr) * 72 + kk * 32 + lg * 8);
#pragma unroll
      for (int ni = 0; ni < 4; ++ni) {
        const s16x8 bfr =
            *(const s16x8*)(K_lds + (ni * 16 + lr) * 72 + kk * 32 + lg * 8);
        s[ni] = __builtin_amdgcn_mfma_f32_16x16x32_bf16(afr, bfr, s[ni], 0, 0, 0);
      }
    }
#pragma unroll
    for (int ni = 0; ni < 4; ++ni)
#pragma unroll
      for (int rr = 0; rr < 4; ++rr) {
        const float p = __expf(s[ni][rr] * 0.125f);
        den[rr] += p;
        P_lds[(w * 16 + lg * 4 + rr) * 72 + ni * 16 + lr] = f2bf(p);
      }
#pragma unroll
    for (int kk = 0; kk < 2; ++kk) {
      const s16x8 pa = *(const s16x8*)(P_lds + (w * 16 + lr) * 72 + kk * 32 + lg * 8);
#pragma unroll
      for (int ni = 0; ni < 4; ++ni) {
        const s16x8 vfr =
            *(const s16x8*)(VT_lds + (ni * 16 + lr) * 72 + kk * 32 + lg * 8);
        num[ni] = __builtin_amdgcn_mfma_f32_16x16x32_bf16(pa, vfr, num[ni], 0, 0, 0);
      }
    }
  }
#pragma unroll
  for (int rr = 0; rr < 4; ++rr) {
#pragma unroll
    for (int o = 1; o < 16; o <<= 1) den[rr] += __shfl_xor(den[rr], o, 64);
  }
  const int obase = (qtr * 128 + bh) * 4096;
#pragma unroll
  for (int ni = 0; ni < 4; ++ni)
    *(f32x4*)(numT + obase + (ni * 16 + lr) * 64 + w * 16 + lg * 4) = num[ni];
  if (lr == 0) {
    f32x4 dv;
#pragma unroll
    for (int rr = 0; rr < 4; ++rr) dv[rr] = den[rr];
    *(f32x4*)(denG + (qtr * 128 + bh) * 64 + w * 16 + lg * 4) = dv;
  }
}

// ------- stage-2 MFMA (aggfin fused): enh[n][C] = softmax49(q.A^T) @ agg -------
__global__ __launch_bounds__(256) void k_attn2(
    const unsigned short* __restrict__ Abf, const float* __restrict__ numT,
    const float* __restrict__ denG, const unsigned short* __restrict__ qbf,
    unsigned short* __restrict__ enh) {
  __shared__ unsigned short A_lds[64 * 72];       // [ag][d]
  __shared__ unsigned short G_lds[64 * 72];       // [d][ag], pre-scaled
  __shared__ unsigned short P2_lds[4][64 * 72];   // per-wave [n][ag]
  __shared__ float invden[64];
  const int blk = blockIdx.x;
  const int bh = blk >> 2, nq = blk & 3;
  const int b = bh >> 3, h = bh & 7;
  const int t = threadIdx.x, w = t >> 6, lane = t & 63;
  const int lr = lane & 15, lg = lane >> 4;

  if (t < 64)
    invden[t] = 1.f / (denG[bh * 64 + t] + denG[8192 + bh * 64 + t] +
                       denG[16384 + bh * 64 + t] + denG[24576 + bh * 64 + t]);
  for (int u = t; u < 15 * 72; u += 256) A_lds[49 * 72 + u] = 0;
  for (int u = t; u < 392; u += 256) {
    const int row = u >> 3, q = u & 7;
    *(s16x8*)(A_lds + row * 72 + q * 8) = *(const s16x8*)(Abf + bh * 4096 + u * 8);
  }
  __syncthreads();  // invden ready
  for (int u = t; u < 4096; u += 256) {  // aggfin fused (same math)
    const int d = u >> 6, ag = u & 63;
    const float v = (numT[bh * 4096 + u] + numT[524288 + bh * 4096 + u] +
                     numT[1048576 + bh * 4096 + u] + numT[1572864 + bh * 4096 + u]) *
                    invden[ag];
    G_lds[d * 72 + ag] = f2bf(v);
  }
  __syncthreads();

  const int nbase = nq * 256 + w * 64;
  const unsigned short* qp = qbf + (bh * 1024 + nbase) * 64;
  s16x8 qf[4][2];
#pragma unroll
  for (int mi = 0; mi < 4; ++mi)
#pragma unroll
    for (int kk = 0; kk < 2; ++kk)
      qf[mi][kk] = *(const s16x8*)(qp + (mi * 16 + lr) * 64 + kk * 32 + lg * 8);

  f32x4 L[4][4];
#pragma unroll
  for (int mi = 0; mi < 4; ++mi)
#pragma unroll
    for (int ni = 0; ni < 4; ++ni)
#pragma unroll
      for (int rr = 0; rr < 4; ++rr) L[mi][ni][rr] = 0.f;
#pragma unroll
  for (int kk = 0; kk < 2; ++kk)
#pragma unroll
    for (int ni = 0; ni < 4; ++ni) {
      const s16x8 bfr = *(const s16x8*)(A_lds + (ni * 16 + lr) * 72 + kk * 32 + lg * 8);
#pragma unroll
      for (int mi = 0; mi < 4; ++mi)
        L[mi][ni] = __builtin_amdgcn_mfma_f32_16x16x32_bf16(qf[mi][kk], bfr,
                                                            L[mi][ni], 0, 0, 0);
    }
  unsigned short* pw = P2_lds[w];
#pragma unroll
  for (int mi = 0; mi < 4; ++mi) {
    float ps[4][4];
    float rs[4];
#pragma unroll
    for (int rr = 0; rr < 4; ++rr) rs[rr] = 0.f;
#pragma unroll
    for (int ni = 0; ni < 4; ++ni) {
      const bool valid = (ni < 3) | (lr == 0);
#pragma unroll
      for (int rr = 0; rr < 4; ++rr) {
        const float p = valid ? __expf(L[mi][ni][rr] * 0.125f) : 0.f;
        ps[ni][rr] = p;
        rs[rr] += p;
      }
    }
#pragma unroll
    for (int rr = 0; rr < 4; ++rr) {
#pragma unroll
      for (int o = 1; o < 16; o <<= 1) rs[rr] += __shfl_xor(rs[rr], o, 64);
      rs[rr] = 1.f / rs[rr];
    }
#pragma unroll
    for (int ni = 0; ni < 4; ++ni)
#pragma unroll
      for (int rr = 0; rr < 4; ++rr)
        pw[(mi * 16 + lg * 4 + rr) * 72 + ni * 16 + lr] = f2bf(ps[ni][rr] * rs[rr]);
  }
#pragma unroll
  for (int mi = 0; mi < 4; ++mi) {
    f32x4 e[4];
#pragma unroll
    for (int ni = 0; ni < 4; ++ni)
#pragma unroll
      for (int rr = 0; rr < 4; ++rr) e[ni][rr] = 0.f;
#pragma unroll
    for (int kk = 0; kk < 2; ++kk) {
      const s16x8 pa = *(const s16x8*)(pw + (mi * 16 + lr) * 72 + kk * 32 + lg * 8);
#pragma unroll
      for (int ni = 0; ni < 4; ++ni) {
        const s16x8 gb = *(const s16x8*)(G_lds + (ni * 16 + lr) * 72 + kk * 32 + lg * 8);
        e[ni] = __builtin_amdgcn_mfma_f32_16x16x32_bf16(pa, gb, e[ni], 0, 0, 0);
      }
    }
#pragma unroll
    for (int ni = 0; ni < 4; ++ni)
#pragma unroll
      for (int rr = 0; rr < 4; ++rr) {
        const int n = nbase + mi * 16 + lg * 4 + rr;
        enh[(b * 1024 + n) * 512 + h * 64 + ni * 16 + lr] = f2bf(e[ni][rr]);
      }
  }
}

extern "C" void kernel_launch(void* const* d_in, const int* in_sizes, int n_in,
                              void* d_out, int out_size, void* d_ws, size_t ws_size,
                              hipStream_t stream) {
  const float* x    = (const float*)d_in[0];
  const float* q_w  = (const float*)d_in[3];
  const float* kv_w = (const float*)d_in[4];
  const float* dw_w = (const float*)d_in[5];
  const float* dw_b = (const float*)d_in[6];
  const float* bn_g = (const float*)d_in[7];
  const float* bn_b = (const float*)d_in[8];
  const float* bn_m = (const float*)d_in[9];
  const float* bn_v = (const float*)d_in[10];
  const float* pw_w = (const float*)d_in[11];
  const float* pw_b = (const float*)d_in[12];
  const float* pj_w = (const float*)d_in[13];
  const float* pj_b = (const float*)d_in[14];
  const float* e1_w = (const float*)d_in[15];
  const float* e1_b = (const float*)d_in[16];
  const float* e2_w = (const float*)d_in[17];
  const float* e2_b = (const float*)d_in[18];

  char* base = (char*)d_ws;
  size_t off = 0;
  auto alloc = [&](size_t bytes) -> void* {
    void* r = base + off;
    off += (bytes + 255) & ~(size_t)255;
    return r;
  };
  unsigned short* Wqkv = (unsigned short*)alloc(786432ull * 2);
  unsigned short* Wpj  = (unsigned short*)alloc(262144ull * 2);
  unsigned short* W1   = (unsigned short*)alloc(262144ull * 2);
  unsigned short* W2   = (unsigned short*)alloc(262144ull * 2);
  unsigned short* xT   = (unsigned short*)alloc(8388608ull * 2);
  unsigned short* qb   = (unsigned short*)alloc(8388608ull * 2);
  unsigned short* kb   = (unsigned short*)alloc(8388608ull * 2);
  unsigned short* vb   = (unsigned short*)alloc(8388608ull * 2);
  float* prow = (float*)alloc(2097152ull * 4);   // 16*512*32*8
  float* pbuf = (float*)alloc(401408ull * 4);
  float* rbuf = (float*)alloc(401408ull * 4);
  unsigned short* Abf = (unsigned short*)alloc(524288ull * 2);  // [bh][ag64][64]
  float* numT = (float*)alloc(2097152ull * 4);   // 4 qtr partials
  float* denG = (float*)alloc(32768ull * 4);
  unsigned short* enh  = (unsigned short*)alloc(8388608ull * 2);
  float* xout = (float*)alloc(8388608ull * 4);
  unsigned short* xoutb = (unsigned short*)alloc(8388608ull * 2);
  unsigned short* h1    = (unsigned short*)alloc(8388608ull * 2);
  (void)ws_size; (void)in_sizes; (void)n_in; (void)out_size;

  k_prep<<<3584, 256, 0, stream>>>(x, xT, prow, q_w, kv_w, pj_w, e1_w, e2_w,
                                   Wqkv, Wpj, W1, W2);
  k_poolred<<<1568, 256, 0, stream>>>(prow, pbuf);
  k_dw<<<2048, 256, 0, stream>>>(pbuf, dw_w, dw_b, bn_g, bn_b, bn_m, bn_v, rbuf);
  k_pw<<<256, 256, 0, stream>>>(rbuf, pw_w, pw_b, Abf);
  k_gemm<0><<<1536, 256, 0, stream>>>(xT, Wqkv, qb, kb, vb,
                                      nullptr, nullptr, nullptr, nullptr, nullptr);
  k_aflash<<<512, 256, 0, stream>>>(Abf, kb, vb, numT, denG);
  k_attn2<<<512, 256, 0, stream>>>(Abf, numT, denG, qb, enh);
  k_gemm<1><<<512, 256, 0, stream>>>(enh, Wpj, nullptr, nullptr, nullptr,
                                     xout, xoutb, pj_b, nullptr, nullptr);
  k_gemm<2><<<512, 256, 0, stream>>>(xoutb, W1, nullptr, nullptr, nullptr,
                                     nullptr, h1, e1_b, nullptr, nullptr);
  k_gemm<3><<<512, 256, 0, stream>>>(h1, W2, nullptr, nullptr, nullptr,
                                     nullptr, nullptr, e2_b, xout, (float*)d_out);
}